// Round 15
// baseline (632.880 us; speedup 1.0000x reference)
//
#include <hip/hip_runtime.h>
#include <hip/hip_fp16.h>

#define NUM_USERS 200000
#define NUM_ITEMS 100000
#define DIM 64
#define NUM_EDGES 2000000
#define BATCH 16384
#define NUM_LAYERS 3

#define NU64 ((size_t)NUM_USERS * DIM)
#define NI64 ((size_t)NUM_ITEMS * DIM)

// bucketed CSR: user buckets = 2048-node ranges, item buckets = 1024-node ranges
#define RU_SHIFT 11
#define RI_SHIFT 10
#define NBU 98   // ceil(200000 / 2048)
#define NBI 98   // ceil(100000 / 1024)
#define CAPU 24576  // fixed capacity per bucket (expected ~20480, 28-sigma margin)
#define CAPI 24576
#define EPB 1024    // edges per scatter block
#define VMASK 0x3FFFF  // 18-bit neighbor id (max 200000 < 262144)

// ---------------- init (fp16 table copies) ----------------

__global__ void convert_kernel(const float4* __restrict__ ut, const float4* __restrict__ it,
                               uint2* __restrict__ uH, uint2* __restrict__ iH) {
    int idx = blockIdx.x * blockDim.x + threadIdx.x;
    const int n4u = (int)(NU64 / 4), n4i = (int)(NI64 / 4);
    if (idx < n4u) {
        float4 v = ut[idx];
        __half2 h0 = __floats2half2_rn(v.x, v.y);
        __half2 h1 = __floats2half2_rn(v.z, v.w);
        uint2 p; p.x = *(unsigned*)&h0; p.y = *(unsigned*)&h1;
        uH[idx] = p;
    } else if (idx < n4u + n4i) {
        int k = idx - n4u;
        float4 v = it[k];
        __half2 h0 = __floats2half2_rn(v.x, v.y);
        __half2 h1 = __floats2half2_rn(v.z, v.w);
        uint2 p; p.x = *(unsigned*)&h0; p.y = *(unsigned*)&h1;
        iH[k] = p;
    }
}

// ---------------- final dot: gather table + 3 layer embs at sampled rows ----------------

__global__ void final_dot_kernel(const float* __restrict__ uT, const float* __restrict__ iT,
                                 const __half* __restrict__ uE1, const __half* __restrict__ uE2,
                                 const __half* __restrict__ uE3,
                                 const __half* __restrict__ iE1, const __half* __restrict__ iE2,
                                 const __half* __restrict__ iE3,
                                 const int* __restrict__ u_idx, const int* __restrict__ i_idx,
                                 float* __restrict__ out) {
    int b    = (blockIdx.x * blockDim.x + threadIdx.x) >> 6;
    int lane = threadIdx.x & 63;
    if (b >= BATCH) return;
    int u = u_idx[b];
    int i = i_idx[b];
    size_t uo = (size_t)u * DIM + lane;
    size_t io = (size_t)i * DIM + lane;
    float su = uT[uo] + __half2float(uE1[uo]) + __half2float(uE2[uo]) + __half2float(uE3[uo]);
    float si = iT[io] + __half2float(iE1[io]) + __half2float(iE2[io]) + __half2float(iE3[io]);
    float p = su * si;
    #pragma unroll
    for (int o = 32; o > 0; o >>= 1) p += __shfl_xor(p, o, 64);
    if (lane == 0) out[b] = p * (1.0f / ((NUM_LAYERS + 1) * (NUM_LAYERS + 1)));
}

// ---------------- CSR construction v3 (packed 4B staging records) ----------------

// Pass A: per-wave-replicated LDS binning, fixed-capacity per-bucket staging.
// Record = (node_offset_in_bucket << 18) | neighbor_id.
__global__ void bucket_scatter(const int* __restrict__ un, const int* __restrict__ in_,
                               int* __restrict__ gcurU, int* __restrict__ gcurI,
                               unsigned* __restrict__ stageU, unsigned* __restrict__ stageI) {
    __shared__ int cntU[4][NBU], cntI[4][NBI];
    __shared__ int baseU[4][NBU], baseI[4][NBI];
    int t = threadIdx.x;
    int w = t >> 6;  // wave 0..3
    for (int k = t; k < 4 * NBU; k += 256) ((int*)cntU)[k] = 0;
    for (int k = t; k < 4 * NBI; k += 256) ((int*)cntI)[k] = 0;
    __syncthreads();
    int e0 = blockIdx.x * EPB + t;
    int u[4], it[4], bu[4], bi[4], ru[4], ri[4];
    bool valid[4];
    #pragma unroll
    for (int k = 0; k < 4; ++k) {
        int e = e0 + k * 256;
        valid[k] = (e < NUM_EDGES);
        if (valid[k]) {
            u[k]  = un[e];
            it[k] = in_[e];
            bu[k] = u[k]  >> RU_SHIFT;
            bi[k] = it[k] >> RI_SHIFT;
            ru[k] = atomicAdd(&cntU[w][bu[k]], 1);
            ri[k] = atomicAdd(&cntI[w][bi[k]], 1);
        }
    }
    __syncthreads();
    if (t < NBU) {
        int c0 = cntU[0][t], c1 = cntU[1][t], c2 = cntU[2][t], c3 = cntU[3][t];
        int b = t * CAPU + atomicAdd(&gcurU[t], c0 + c1 + c2 + c3);
        baseU[0][t] = b; baseU[1][t] = b + c0; baseU[2][t] = b + c0 + c1; baseU[3][t] = b + c0 + c1 + c2;
    }
    if (t < NBI) {
        int c0 = cntI[0][t], c1 = cntI[1][t], c2 = cntI[2][t], c3 = cntI[3][t];
        int b = t * CAPI + atomicAdd(&gcurI[t], c0 + c1 + c2 + c3);
        baseI[0][t] = b; baseI[1][t] = b + c0; baseI[2][t] = b + c0 + c1; baseI[3][t] = b + c0 + c1 + c2;
    }
    __syncthreads();
    #pragma unroll
    for (int k = 0; k < 4; ++k) {
        if (valid[k]) {
            stageU[baseU[w][bu[k]] + ru[k]] = ((unsigned)(u[k]  & ((1 << RU_SHIFT) - 1)) << 18) | (unsigned)it[k];
            stageI[baseI[w][bi[k]] + ri[k]] = ((unsigned)(it[k] & ((1 << RI_SHIFT) - 1)) << 18) | (unsigned)u[k];
        }
    }
}

// Pass B: one block per bucket. Per-node counts + LDS prefix scan produce
// offs/deg locally, then place records with LDS cursors.
__global__ void bucket_place(const int* __restrict__ gcurU, const int* __restrict__ gcurI,
                             const unsigned* __restrict__ stageU, const unsigned* __restrict__ stageI,
                             int* __restrict__ u_offs, int* __restrict__ i_offs,
                             int* __restrict__ u_deg, int* __restrict__ i_deg,
                             int* __restrict__ u_adj, int* __restrict__ i_adj) {
    __shared__ int cnt[2048];
    __shared__ int offs_l[2048];
    __shared__ int wsum[1024];
    int b = blockIdx.x, t = threadIdx.x;
    const unsigned* stage; int* adj; int* offs; int* deg; int lo, range, nrec, bbase;
    if (b < NBU) {
        stage = stageU + (size_t)b * CAPU; adj = u_adj; offs = u_offs; deg = u_deg;
        nrec = gcurU[b]; lo = b << RU_SHIFT; bbase = b * CAPU;
        range = NUM_USERS - lo; if (range > 2048) range = 2048;
    } else {
        int bb = b - NBU;
        stage = stageI + (size_t)bb * CAPI; adj = i_adj; offs = i_offs; deg = i_deg;
        nrec = gcurI[bb]; lo = bb << RI_SHIFT; bbase = bb * CAPI;
        range = NUM_ITEMS - lo; if (range > 1024) range = 1024;
    }
    cnt[t] = 0; cnt[t + 1024] = 0;
    __syncthreads();
    for (int r = t; r < nrec; r += 1024) atomicAdd(&cnt[stage[r] >> 18], 1);
    __syncthreads();
    int c0 = cnt[2 * t], c1 = cnt[2 * t + 1];
    int s = c0 + c1;
    wsum[t] = s;
    __syncthreads();
    for (int off = 1; off < 1024; off <<= 1) {
        int v = (t >= off) ? wsum[t - off] : 0;
        __syncthreads();
        wsum[t] += v;
        __syncthreads();
    }
    int excl = wsum[t] - s;  // exclusive prefix of node 2t
    offs_l[2 * t] = excl;
    offs_l[2 * t + 1] = excl + c0;
    if (2 * t < range)     { offs[lo + 2 * t]     = bbase + excl;      deg[lo + 2 * t]     = c0; }
    if (2 * t + 1 < range) { offs[lo + 2 * t + 1] = bbase + excl + c0; deg[lo + 2 * t + 1] = c1; }
    cnt[2 * t] = 0; cnt[2 * t + 1] = 0;   // reuse as placement cursors
    __syncthreads();
    for (int r = t; r < nrec; r += 1024) {
        unsigned rec = stage[r];
        int loc = (int)(rec >> 18);
        int p = atomicAdd(&cnt[loc], 1);
        adj[bbase + offs_l[loc] + p] = (int)(rec & VMASK);
    }
}

// ---------------- fused pull + normalize (scalarized neighbor loop) ----------------
// One wave per row; lane = dim (identity mapping), one neighbor per step.
// row/start/cnt/adj[start+j] are wave-uniform -> scalar loads + SALU row bases;
// per-lane cost per neighbor: 1 addr fold + 1 load(2B) + 1 cvt + 1 add.
__global__ void pull_norm_kernel(const int* __restrict__ u_offs, const int* __restrict__ u_deg,
                                 const int* __restrict__ u_adj,
                                 const int* __restrict__ i_offs, const int* __restrict__ i_deg,
                                 const int* __restrict__ i_adj,
                                 const __half* __restrict__ uprev, const __half* __restrict__ iprev,
                                 __half* __restrict__ unew, __half* __restrict__ inew) {
    int w    = (blockIdx.x * blockDim.x + threadIdx.x) >> 6;
    int lane = threadIdx.x & 63;
    const int* offs; const int* deg; const int* adj; const __half* src; __half* demb; int row;
    if (w < NUM_USERS) {
        row = w; offs = u_offs; deg = u_deg; adj = u_adj; src = iprev; demb = unew;
    } else {
        row = w - NUM_USERS;
        if (row >= NUM_ITEMS) return;
        offs = i_offs; deg = i_deg; adj = i_adj; src = uprev; demb = inew;
    }
    row = __builtin_amdgcn_readfirstlane(row);
    int start = __builtin_amdgcn_readfirstlane(offs[row]);
    int cnt   = __builtin_amdgcn_readfirstlane(deg[row]);
    float a = 0.0f;
    int j = 0;
    for (; j + 4 <= cnt; j += 4) {
        int n0 = adj[start + j];
        int n1 = adj[start + j + 1];
        int n2 = adj[start + j + 2];
        int n3 = adj[start + j + 3];
        float v0 = __half2float(src[(size_t)n0 * DIM + lane]);
        float v1 = __half2float(src[(size_t)n1 * DIM + lane]);
        float v2 = __half2float(src[(size_t)n2 * DIM + lane]);
        float v3 = __half2float(src[(size_t)n3 * DIM + lane]);
        a += (v0 + v1) + (v2 + v3);
    }
    for (; j < cnt; ++j) {
        int nb = adj[start + j];
        a += __half2float(src[(size_t)nb * DIM + lane]);
    }
    float ss = a * a;
    #pragma unroll
    for (int o = 32; o > 0; o >>= 1) ss += __shfl_xor(ss, o, 64);
    float inv = 1.0f / fmaxf(sqrtf(ss), 1e-12f);
    demb[(size_t)row * DIM + lane] = __float2half(a * inv);
}

// ---------------- launch ----------------

extern "C" void kernel_launch(void* const* d_in, const int* in_sizes, int n_in,
                              void* d_out, int out_size, void* d_ws, size_t ws_size,
                              hipStream_t stream) {
    const float* user_table = (const float*)d_in[0];
    const float* item_table = (const float*)d_in[1];
    const int*   u_idx      = (const int*)d_in[2];
    const int*   i_idx      = (const int*)d_in[3];
    const int*   edges      = (const int*)d_in[4];
    const int*   u_nodes    = edges;              // edge_index[0]
    const int*   i_nodes    = edges + NUM_EDGES;  // edge_index[1]
    float*       out        = (float*)d_out;

    // ---- workspace layout (~130 MB) ----
    __half* uH0 = (__half*)d_ws;        // fp16 table copy (25.6 MB)
    __half* uE1 = uH0 + NU64;           // layer-1 user emb
    __half* uE2 = uE1 + NU64;           // layer-2
    __half* uE3 = uE2 + NU64;           // layer-3
    __half* iH0 = uE3 + NU64;           // fp16 item table copy (12.8 MB)
    __half* iE1 = iH0 + NI64;
    __half* iE2 = iE1 + NI64;
    __half* iE3 = iE2 + NI64;

    int* ip     = (int*)(iE3 + NI64);
    int* u_offs = ip;                        // NUM_USERS
    int* i_offs = u_offs + NUM_USERS;        // NUM_ITEMS
    int* u_deg  = i_offs + NUM_ITEMS;        // NUM_USERS
    int* i_deg  = u_deg + NUM_USERS;         // NUM_ITEMS
    int* u_adj  = i_deg + NUM_ITEMS;         // NBU*CAPU (9.6 MB)
    int* i_adj  = u_adj + (size_t)NBU * CAPU;  // NBI*CAPI (9.6 MB)
    int* gcurU  = i_adj + (size_t)NBI * CAPI;  // NBU
    int* gcurI  = gcurU + NBU;               // NBI
    unsigned* stageU = (unsigned*)(gcurI + NBI);      // NBU*CAPU u32 (9.6 MB)
    unsigned* stageI = stageU + (size_t)NBU * CAPU;   // NBI*CAPI u32 (9.6 MB)

    // ---- init: fp16 copies of the tables ----
    {
        int n4 = (int)((NU64 + NI64) / 4);
        convert_kernel<<<(n4 + 255) / 256, 256, 0, stream>>>(
            (const float4*)user_table, (const float4*)item_table,
            (uint2*)uH0, (uint2*)iH0);
    }

    // ---- CSR build v3 ----
    hipMemsetAsync(gcurU, 0, (NBU + NBI) * sizeof(int), stream);

    int nblkA = (NUM_EDGES + EPB - 1) / EPB;
    bucket_scatter<<<nblkA, 256, 0, stream>>>(u_nodes, i_nodes, gcurU, gcurI, stageU, stageI);
    bucket_place<<<NBU + NBI, 1024, 0, stream>>>(gcurU, gcurI, stageU, stageI,
                                                 u_offs, i_offs, u_deg, i_deg, u_adj, i_adj);

    // ---- 3 fused pull layers (fp16 gathers; each layer's emb persisted) ----
    long long waves = (long long)(NUM_USERS + NUM_ITEMS);
    int blocks = (int)((waves * 64 + 255) / 256);
    const __half* uprevs[3] = {uH0, uE1, uE2};
    const __half* iprevs[3] = {iH0, iE1, iE2};
    __half* udsts[3] = {uE1, uE2, uE3};
    __half* idsts[3] = {iE1, iE2, iE3};
    for (int l = 0; l < NUM_LAYERS; ++l) {
        pull_norm_kernel<<<blocks, 256, 0, stream>>>(u_offs, u_deg, u_adj,
                                                     i_offs, i_deg, i_adj,
                                                     uprevs[l], iprevs[l],
                                                     udsts[l], idsts[l]);
    }

    // ---- final dot over sampled rows: (table + e1 + e2 + e3) . (table + e1 + e2 + e3) / 16 ----
    {
        long long tb = (long long)BATCH * 64;
        final_dot_kernel<<<(int)((tb + 255) / 256), 256, 0, stream>>>(
            user_table, item_table, uE1, uE2, uE3, iE1, iE2, iE3, u_idx, i_idx, out);
    }
}

// Round 17
// 500.730 us; speedup vs baseline: 1.2639x; 1.2639x over previous
//
#include <hip/hip_runtime.h>
#include <hip/hip_fp16.h>

#define NUM_USERS 200000
#define NUM_ITEMS 100000
#define DIM 64
#define NUM_EDGES 2000000
#define BATCH 16384
#define NUM_LAYERS 3

#define NU64 ((size_t)NUM_USERS * DIM)
#define NI64 ((size_t)NUM_ITEMS * DIM)

// bucketed CSR: user buckets = 2048-node ranges, item buckets = 1024-node ranges
#define RU_SHIFT 11
#define RI_SHIFT 10
#define NBU 98   // ceil(200000 / 2048)
#define NBI 98   // ceil(100000 / 1024)
#define CAPU 24576  // fixed capacity per bucket (expected ~20480, 28-sigma margin)
#define CAPI 24576
#define EPB 1024    // edges per scatter block
#define VMASK 0x3FFFF  // 18-bit neighbor id (max 200000 < 262144)

// ---------------- init (fp16 table copies) ----------------

__global__ void convert_kernel(const float4* __restrict__ ut, const float4* __restrict__ it,
                               uint2* __restrict__ uH, uint2* __restrict__ iH) {
    int idx = blockIdx.x * blockDim.x + threadIdx.x;
    const int n4u = (int)(NU64 / 4), n4i = (int)(NI64 / 4);
    if (idx < n4u) {
        float4 v = ut[idx];
        __half2 h0 = __floats2half2_rn(v.x, v.y);
        __half2 h1 = __floats2half2_rn(v.z, v.w);
        uint2 p; p.x = *(unsigned*)&h0; p.y = *(unsigned*)&h1;
        uH[idx] = p;
    } else if (idx < n4u + n4i) {
        int k = idx - n4u;
        float4 v = it[k];
        __half2 h0 = __floats2half2_rn(v.x, v.y);
        __half2 h1 = __floats2half2_rn(v.z, v.w);
        uint2 p; p.x = *(unsigned*)&h0; p.y = *(unsigned*)&h1;
        iH[k] = p;
    }
}

// ---------------- final dot: gather table + 3 layer embs at sampled rows ----------------

__global__ void final_dot_kernel(const float* __restrict__ uT, const float* __restrict__ iT,
                                 const __half* __restrict__ uE1, const __half* __restrict__ uE2,
                                 const __half* __restrict__ uE3,
                                 const __half* __restrict__ iE1, const __half* __restrict__ iE2,
                                 const __half* __restrict__ iE3,
                                 const int* __restrict__ u_idx, const int* __restrict__ i_idx,
                                 float* __restrict__ out) {
    int b    = (blockIdx.x * blockDim.x + threadIdx.x) >> 6;
    int lane = threadIdx.x & 63;
    if (b >= BATCH) return;
    int u = u_idx[b];
    int i = i_idx[b];
    size_t uo = (size_t)u * DIM + lane;
    size_t io = (size_t)i * DIM + lane;
    float su = uT[uo] + __half2float(uE1[uo]) + __half2float(uE2[uo]) + __half2float(uE3[uo]);
    float si = iT[io] + __half2float(iE1[io]) + __half2float(iE2[io]) + __half2float(iE3[io]);
    float p = su * si;
    #pragma unroll
    for (int o = 32; o > 0; o >>= 1) p += __shfl_xor(p, o, 64);
    if (lane == 0) out[b] = p * (1.0f / ((NUM_LAYERS + 1) * (NUM_LAYERS + 1)));
}

// ---------------- CSR construction v3 (packed 4B staging records) ----------------

// Pass A: per-wave-replicated LDS binning, fixed-capacity per-bucket staging.
// Record = (node_offset_in_bucket << 18) | neighbor_id.
__global__ void bucket_scatter(const int* __restrict__ un, const int* __restrict__ in_,
                               int* __restrict__ gcurU, int* __restrict__ gcurI,
                               unsigned* __restrict__ stageU, unsigned* __restrict__ stageI) {
    __shared__ int cntU[4][NBU], cntI[4][NBI];
    __shared__ int baseU[4][NBU], baseI[4][NBI];
    int t = threadIdx.x;
    int w = t >> 6;  // wave 0..3
    for (int k = t; k < 4 * NBU; k += 256) ((int*)cntU)[k] = 0;
    for (int k = t; k < 4 * NBI; k += 256) ((int*)cntI)[k] = 0;
    __syncthreads();
    int e0 = blockIdx.x * EPB + t;
    int u[4], it[4], bu[4], bi[4], ru[4], ri[4];
    bool valid[4];
    #pragma unroll
    for (int k = 0; k < 4; ++k) {
        int e = e0 + k * 256;
        valid[k] = (e < NUM_EDGES);
        if (valid[k]) {
            u[k]  = un[e];
            it[k] = in_[e];
            bu[k] = u[k]  >> RU_SHIFT;
            bi[k] = it[k] >> RI_SHIFT;
            ru[k] = atomicAdd(&cntU[w][bu[k]], 1);
            ri[k] = atomicAdd(&cntI[w][bi[k]], 1);
        }
    }
    __syncthreads();
    if (t < NBU) {
        int c0 = cntU[0][t], c1 = cntU[1][t], c2 = cntU[2][t], c3 = cntU[3][t];
        int b = t * CAPU + atomicAdd(&gcurU[t], c0 + c1 + c2 + c3);
        baseU[0][t] = b; baseU[1][t] = b + c0; baseU[2][t] = b + c0 + c1; baseU[3][t] = b + c0 + c1 + c2;
    }
    if (t < NBI) {
        int c0 = cntI[0][t], c1 = cntI[1][t], c2 = cntI[2][t], c3 = cntI[3][t];
        int b = t * CAPI + atomicAdd(&gcurI[t], c0 + c1 + c2 + c3);
        baseI[0][t] = b; baseI[1][t] = b + c0; baseI[2][t] = b + c0 + c1; baseI[3][t] = b + c0 + c1 + c2;
    }
    __syncthreads();
    #pragma unroll
    for (int k = 0; k < 4; ++k) {
        if (valid[k]) {
            stageU[baseU[w][bu[k]] + ru[k]] = ((unsigned)(u[k]  & ((1 << RU_SHIFT) - 1)) << 18) | (unsigned)it[k];
            stageI[baseI[w][bi[k]] + ri[k]] = ((unsigned)(it[k] & ((1 << RI_SHIFT) - 1)) << 18) | (unsigned)u[k];
        }
    }
}

// Pass B: one block per bucket. Per-node counts + LDS prefix scan produce
// offs/deg locally, then place records with LDS cursors.
__global__ void bucket_place(const int* __restrict__ gcurU, const int* __restrict__ gcurI,
                             const unsigned* __restrict__ stageU, const unsigned* __restrict__ stageI,
                             int* __restrict__ u_offs, int* __restrict__ i_offs,
                             int* __restrict__ u_deg, int* __restrict__ i_deg,
                             int* __restrict__ u_adj, int* __restrict__ i_adj) {
    __shared__ int cnt[2048];
    __shared__ int offs_l[2048];
    __shared__ int wsum[1024];
    int b = blockIdx.x, t = threadIdx.x;
    const unsigned* stage; int* adj; int* offs; int* deg; int lo, range, nrec, bbase;
    if (b < NBU) {
        stage = stageU + (size_t)b * CAPU; adj = u_adj; offs = u_offs; deg = u_deg;
        nrec = gcurU[b]; lo = b << RU_SHIFT; bbase = b * CAPU;
        range = NUM_USERS - lo; if (range > 2048) range = 2048;
    } else {
        int bb = b - NBU;
        stage = stageI + (size_t)bb * CAPI; adj = i_adj; offs = i_offs; deg = i_deg;
        nrec = gcurI[bb]; lo = bb << RI_SHIFT; bbase = bb * CAPI;
        range = NUM_ITEMS - lo; if (range > 1024) range = 1024;
    }
    cnt[t] = 0; cnt[t + 1024] = 0;
    __syncthreads();
    for (int r = t; r < nrec; r += 1024) atomicAdd(&cnt[stage[r] >> 18], 1);
    __syncthreads();
    int c0 = cnt[2 * t], c1 = cnt[2 * t + 1];
    int s = c0 + c1;
    wsum[t] = s;
    __syncthreads();
    for (int off = 1; off < 1024; off <<= 1) {
        int v = (t >= off) ? wsum[t - off] : 0;
        __syncthreads();
        wsum[t] += v;
        __syncthreads();
    }
    int excl = wsum[t] - s;  // exclusive prefix of node 2t
    offs_l[2 * t] = excl;
    offs_l[2 * t + 1] = excl + c0;
    if (2 * t < range)     { offs[lo + 2 * t]     = bbase + excl;      deg[lo + 2 * t]     = c0; }
    if (2 * t + 1 < range) { offs[lo + 2 * t + 1] = bbase + excl + c0; deg[lo + 2 * t + 1] = c1; }
    cnt[2 * t] = 0; cnt[2 * t + 1] = 0;   // reuse as placement cursors
    __syncthreads();
    for (int r = t; r < nrec; r += 1024) {
        unsigned rec = stage[r];
        int loc = (int)(rec >> 18);
        int p = atomicAdd(&cnt[loc], 1);
        adj[bbase + offs_l[loc] + p] = (int)(rec & VMASK);
    }
}

// ---------------- fused pull + normalize (r14-proven float2 half-split, unroll-8) ----------------
// One wave per row; lanes 0-31 process neighbor j, lanes 32-63 neighbor j+1,
// each lane loads __half2 (4B) = 2 dims; 8 pair-loads (2KB) in flight per wave.
__global__ void pull_norm_kernel(const int* __restrict__ u_offs, const int* __restrict__ u_deg,
                                 const int* __restrict__ u_adj,
                                 const int* __restrict__ i_offs, const int* __restrict__ i_deg,
                                 const int* __restrict__ i_adj,
                                 const __half* __restrict__ uprev, const __half* __restrict__ iprev,
                                 __half* __restrict__ unew, __half* __restrict__ inew) {
    int w    = (blockIdx.x * blockDim.x + threadIdx.x) >> 6;
    int lane = threadIdx.x & 63;
    int half = lane >> 5;   // 0 or 1
    int l32  = lane & 31;
    const int* offs; const int* deg; const int* adj; const __half* src; __half* demb; int row;
    if (w < NUM_USERS) {
        row = w; offs = u_offs; deg = u_deg; adj = u_adj; src = iprev; demb = unew;
    } else {
        row = w - NUM_USERS;
        if (row >= NUM_ITEMS) return;
        offs = i_offs; deg = i_deg; adj = i_adj; src = uprev; demb = inew;
    }
    int start = offs[row];
    int cnt   = deg[row];
    float ax = 0.0f, ay = 0.0f;
    for (int base = 0; base < cnt; base += 64) {
        int rem = cnt - base;
        if (rem > 64) rem = 64;
        int idx = (lane < rem) ? adj[start + base + lane] : 0;
        int j = 0;
        // 8 pairs (16 neighbors) per unrolled iteration: 8 independent 256B loads in flight
        for (; j + 16 <= rem; j += 16) {
            #pragma unroll
            for (int p = 0; p < 8; ++p) {
                int nb = __shfl(idx, j + 2 * p + half, 64);
                const __half2* srow = (const __half2*)(src + (size_t)nb * DIM);
                float2 v = __half22float2(srow[l32]);
                ax += v.x; ay += v.y;
            }
        }
        // 4 pairs (8 neighbors)
        for (; j + 8 <= rem; j += 8) {
            #pragma unroll
            for (int p = 0; p < 4; ++p) {
                int nb = __shfl(idx, j + 2 * p + half, 64);
                const __half2* srow = (const __half2*)(src + (size_t)nb * DIM);
                float2 v = __half22float2(srow[l32]);
                ax += v.x; ay += v.y;
            }
        }
        for (; j + 2 <= rem; j += 2) {
            int nb = __shfl(idx, j + half, 64);
            const __half2* srow = (const __half2*)(src + (size_t)nb * DIM);
            float2 v = __half22float2(srow[l32]);
            ax += v.x; ay += v.y;
        }
        if (j < rem) {  // odd leftover neighbor: lanes 0-31 only
            int nb = __shfl(idx, j, 64);
            const __half2* srow = (const __half2*)(src + (size_t)nb * DIM);
            float2 v = __half22float2(srow[l32]);
            if (half == 0) { ax += v.x; ay += v.y; }
        }
    }
    // merge the two half-wave partial sums
    ax += __shfl_xor(ax, 32, 64);
    ay += __shfl_xor(ay, 32, 64);
    float ss = ax * ax + ay * ay;
    #pragma unroll
    for (int o = 16; o > 0; o >>= 1) ss += __shfl_xor(ss, o, 64);
    float inv = 1.0f / fmaxf(sqrtf(ss), 1e-12f);
    float nx = ax * inv, ny = ay * inv;
    if (half == 0) {
        ((__half2*)(demb + (size_t)row * DIM))[l32] = __floats2half2_rn(nx, ny);
    }
}

// ---------------- launch ----------------

extern "C" void kernel_launch(void* const* d_in, const int* in_sizes, int n_in,
                              void* d_out, int out_size, void* d_ws, size_t ws_size,
                              hipStream_t stream) {
    const float* user_table = (const float*)d_in[0];
    const float* item_table = (const float*)d_in[1];
    const int*   u_idx      = (const int*)d_in[2];
    const int*   i_idx      = (const int*)d_in[3];
    const int*   edges      = (const int*)d_in[4];
    const int*   u_nodes    = edges;              // edge_index[0]
    const int*   i_nodes    = edges + NUM_EDGES;  // edge_index[1]
    float*       out        = (float*)d_out;

    // ---- workspace layout (~130 MB) ----
    __half* uH0 = (__half*)d_ws;        // fp16 table copy (25.6 MB)
    __half* uE1 = uH0 + NU64;           // layer-1 user emb
    __half* uE2 = uE1 + NU64;           // layer-2
    __half* uE3 = uE2 + NU64;           // layer-3
    __half* iH0 = uE3 + NU64;           // fp16 item table copy (12.8 MB)
    __half* iE1 = iH0 + NI64;
    __half* iE2 = iE1 + NI64;
    __half* iE3 = iE2 + NI64;

    int* ip     = (int*)(iE3 + NI64);
    int* u_offs = ip;                        // NUM_USERS
    int* i_offs = u_offs + NUM_USERS;        // NUM_ITEMS
    int* u_deg  = i_offs + NUM_ITEMS;        // NUM_USERS
    int* i_deg  = u_deg + NUM_USERS;         // NUM_ITEMS
    int* u_adj  = i_deg + NUM_ITEMS;         // NBU*CAPU (9.6 MB)
    int* i_adj  = u_adj + (size_t)NBU * CAPU;  // NBI*CAPI (9.6 MB)
    int* gcurU  = i_adj + (size_t)NBI * CAPI;  // NBU
    int* gcurI  = gcurU + NBU;               // NBI
    unsigned* stageU = (unsigned*)(gcurI + NBI);      // NBU*CAPU u32 (9.6 MB)
    unsigned* stageI = stageU + (size_t)NBU * CAPU;   // NBI*CAPI u32 (9.6 MB)

    // ---- init: fp16 copies of the tables ----
    {
        int n4 = (int)((NU64 + NI64) / 4);
        convert_kernel<<<(n4 + 255) / 256, 256, 0, stream>>>(
            (const float4*)user_table, (const float4*)item_table,
            (uint2*)uH0, (uint2*)iH0);
    }

    // ---- CSR build v3 ----
    hipMemsetAsync(gcurU, 0, (NBU + NBI) * sizeof(int), stream);

    int nblkA = (NUM_EDGES + EPB - 1) / EPB;
    bucket_scatter<<<nblkA, 256, 0, stream>>>(u_nodes, i_nodes, gcurU, gcurI, stageU, stageI);
    bucket_place<<<NBU + NBI, 1024, 0, stream>>>(gcurU, gcurI, stageU, stageI,
                                                 u_offs, i_offs, u_deg, i_deg, u_adj, i_adj);

    // ---- 3 fused pull layers (fp16 gathers; each layer's emb persisted) ----
    long long waves = (long long)(NUM_USERS + NUM_ITEMS);
    int blocks = (int)((waves * 64 + 255) / 256);
    const __half* uprevs[3] = {uH0, uE1, uE2};
    const __half* iprevs[3] = {iH0, iE1, iE2};
    __half* udsts[3] = {uE1, uE2, uE3};
    __half* idsts[3] = {iE1, iE2, iE3};
    for (int l = 0; l < NUM_LAYERS; ++l) {
        pull_norm_kernel<<<blocks, 256, 0, stream>>>(u_offs, u_deg, u_adj,
                                                     i_offs, i_deg, i_adj,
                                                     uprevs[l], iprevs[l],
                                                     udsts[l], idsts[l]);
    }

    // ---- final dot over sampled rows: (table + e1 + e2 + e3) . (table + e1 + e2 + e3) / 16 ----
    {
        long long tb = (long long)BATCH * 64;
        final_dot_kernel<<<(int)((tb + 255) / 256), 256, 0, stream>>>(
            user_table, item_table, uE1, uE2, uE3, iE1, iE2, iE3, u_idx, i_idx, out);
    }
}